// Round 1
// baseline (730.314 us; speedup 1.0000x reference)
//
#include <hip/hip_runtime.h>
#include <math.h>

// GGAM: windowed (41x41) gaussian-guided attention, b=2 c=128 h=48 w=64.
// Strategy: never materialize hw x hw. Window-only logits + softmax stats +
// gather-form reverse-scatter aggregation. fp32 everywhere (round 1).

namespace {
constexpr int BB   = 2;
constexpr int CD   = 128;   // channels
constexpr int HH   = 48;
constexpr int WD   = 64;
constexpr int HWN  = 3072;
constexpr int KWIN = 41;
constexpr int RAD  = 20;
constexpr int NKK  = 1681;  // 41*41
constexpr int KKP  = 1684;  // padded row stride (float4-aligned)

// workspace layout (in floats)
constexpr size_t OFF_CORR  = 0;
constexpr size_t SZ_CORR   = (size_t)BB * HWN * KKP;          // 10,346,496
constexpr size_t OFF_Q     = OFF_CORR + SZ_CORR;
constexpr size_t OFF_K     = OFF_Q + (size_t)BB * HWN * CD;
constexpr size_t OFF_V     = OFF_K + (size_t)BB * HWN * CD;
constexpr size_t OFF_FEAT  = OFF_V + (size_t)BB * HWN * CD;
constexpr size_t OFF_META  = OFF_FEAT + (size_t)BB * HWN;     // float4/pixel
constexpr size_t OFF_STATS = OFF_META + (size_t)BB * HWN * 4; // float2/query
} // namespace

__device__ __forceinline__ float dot4(float4 a, float4 b, float acc) {
  return fmaf(a.x, b.x, fmaf(a.y, b.y, fmaf(a.z, b.z, fmaf(a.w, b.w, acc))));
}

// thresholded gaussian: exp(-r2/800)*2.5+10, zero when r2 > 800*ln(10).
// r2 is an exact small integer in fp32; cutoff r2<=1842 matches the
// reference's  g < BI+THR*SC_G  decision with huge margin.
__device__ __forceinline__ float gthr(float dy, float dx) {
  float r2 = fmaf(dy, dy, dx * dx);
  float g  = fmaf(__expf(r2 * (-1.0f / 800.0f)), 2.5f, 10.0f);
  return (r2 <= 1842.0f) ? g : 0.0f;
}

__device__ __forceinline__ float bilin_g(const float* mt, float ny, float nx) {
  float y0 = mt[0], y1 = mt[1], fy = mt[2];
  float x0 = mt[3], x1 = mt[4], fx = mt[5];
  float g00 = gthr(y0 - ny, x0 - nx);
  float g01 = gthr(y0 - ny, x1 - nx);
  float g10 = gthr(y1 - ny, x0 - nx);
  float g11 = gthr(y1 - ny, x1 - nx);
  float top = (1.0f - fx) * g00 + fx * g01;
  float bot = (1.0f - fx) * g10 + fx * g11;
  return (1.0f - fy) * top + fy * bot;
}

// ---------------- qkv: q(scaled)/k = w_qk @ feat_ctx, v = w_v @ feat_mo ----
// grid: B*96*2 blocks, 256 thr. Each block: 32 spatial cols, 192 output rows.
__global__ __launch_bounds__(256) void qkv_kernel(
    const float* __restrict__ fctx, const float* __restrict__ fmo,
    const float* __restrict__ wqk, const float* __restrict__ wv,
    float* __restrict__ ws) {
  __shared__ float xc[128][36];
  __shared__ float xm[128][36];
  int blk = blockIdx.x;
  int b = blk / 192;
  int rem = blk % 192;
  int tile = rem >> 1;
  int half = rem & 1;
  int n0 = tile * 32;
  int t = threadIdx.x;

#pragma unroll
  for (int i = 0; i < 4; ++i) {
    int chunk = t + 256 * i;
    int c = chunk >> 3, nc = chunk & 7;
    *(float4*)&xc[c][nc * 4] =
        *(const float4*)(fctx + ((size_t)b * CD + c) * HWN + n0 + nc * 4);
  }
  if (half) {
#pragma unroll
    for (int i = 0; i < 4; ++i) {
      int chunk = t + 256 * i;
      int c = chunk >> 3, nc = chunk & 7;
      *(float4*)&xm[c][nc * 4] =
          *(const float4*)(fmo + ((size_t)b * CD + c) * HWN + n0 + nc * 4);
    }
  }
  __syncthreads();

  int ng = t & 7, og = t >> 3;  // og 0..31
  const float* wrow[6];
  bool useM[6];
#pragma unroll
  for (int j = 0; j < 6; ++j) {
    int r = half * 192 + og + 32 * j;
    if (r < 256) { wrow[j] = wqk + (size_t)r * CD; useM[j] = false; }
    else         { wrow[j] = wv + (size_t)(r - 256) * CD; useM[j] = true; }
  }
  float acc[6][4];
#pragma unroll
  for (int j = 0; j < 6; ++j)
#pragma unroll
    for (int nn = 0; nn < 4; ++nn) acc[j][nn] = 0.0f;

  for (int c4 = 0; c4 < 32; ++c4) {
    float4 xa0 = *(const float4*)&xc[c4 * 4 + 0][ng * 4];
    float4 xa1 = *(const float4*)&xc[c4 * 4 + 1][ng * 4];
    float4 xa2 = *(const float4*)&xc[c4 * 4 + 2][ng * 4];
    float4 xa3 = *(const float4*)&xc[c4 * 4 + 3][ng * 4];
    float4 xm0, xm1, xm2, xm3;
    if (half) {
      xm0 = *(const float4*)&xm[c4 * 4 + 0][ng * 4];
      xm1 = *(const float4*)&xm[c4 * 4 + 1][ng * 4];
      xm2 = *(const float4*)&xm[c4 * 4 + 2][ng * 4];
      xm3 = *(const float4*)&xm[c4 * 4 + 3][ng * 4];
    }
#pragma unroll
    for (int j = 0; j < 6; ++j) {
      float4 w4 = *(const float4*)(wrow[j] + c4 * 4);
      float4 x0 = (half && useM[j]) ? xm0 : xa0;
      float4 x1 = (half && useM[j]) ? xm1 : xa1;
      float4 x2 = (half && useM[j]) ? xm2 : xa2;
      float4 x3 = (half && useM[j]) ? xm3 : xa3;
      acc[j][0] = fmaf(w4.x, x0.x, fmaf(w4.y, x1.x, fmaf(w4.z, x2.x, fmaf(w4.w, x3.x, acc[j][0]))));
      acc[j][1] = fmaf(w4.x, x0.y, fmaf(w4.y, x1.y, fmaf(w4.z, x2.y, fmaf(w4.w, x3.y, acc[j][1]))));
      acc[j][2] = fmaf(w4.x, x0.z, fmaf(w4.y, x1.z, fmaf(w4.z, x2.z, fmaf(w4.w, x3.z, acc[j][2]))));
      acc[j][3] = fmaf(w4.x, x0.w, fmaf(w4.y, x1.w, fmaf(w4.z, x2.w, fmaf(w4.w, x3.w, acc[j][3]))));
    }
  }

  const float qscale = 0.08838834764831845f;  // 128^-0.5
#pragma unroll
  for (int j = 0; j < 6; ++j) {
    int r = half * 192 + og + 32 * j;
    float* dst;
    float mul = 1.0f;
    int rr;
    if (r < 128)      { dst = ws + OFF_Q; rr = r;       mul = qscale; }
    else if (r < 256) { dst = ws + OFF_K; rr = r - 128; }
    else              { dst = ws + OFF_V; rr = r - 256; }
    size_t nbase = (size_t)b * HWN + n0 + ng * 4;
#pragma unroll
    for (int nn = 0; nn < 4; ++nn)
      dst[(nbase + nn) * CD + rr] = acc[j][nn] * mul;
  }
}

// ---------------- channel mean of feat_mo -> feat[b][n] -------------------
__global__ __launch_bounds__(256) void mean_kernel(
    const float* __restrict__ fmo, float* __restrict__ ws) {
  __shared__ float red[4][64];
  int t = threadIdx.x;
  int nl = t & 63, cgp = t >> 6;
  int p = blockIdx.x * 64 + nl;  // 0 .. B*HW-1 (96 blocks)
  const float* src = fmo + (size_t)(p / HWN) * CD * HWN + (p % HWN);
  float s = 0.0f;
  for (int c = cgp * 32; c < cgp * 32 + 32; ++c) s += src[(size_t)c * HWN];
  red[cgp][nl] = s;
  __syncthreads();
  if (cgp == 0) {
    float tot = red[0][nl] + red[1][nl] + red[2][nl] + red[3][nl];
    ws[OFF_FEAT + p] = tot * (1.0f / 128.0f);
  }
}

// ---------------- DGM: depthwise conv -> offsets -> (py,px,ga) meta -------
__global__ __launch_bounds__(256) void dgm_kernel(
    const float* __restrict__ win, const float* __restrict__ bin,
    const float* __restrict__ wdw, const float* __restrict__ bdw,
    const float* __restrict__ wofs, const float* __restrict__ wa,
    const float* __restrict__ ba, const float* __restrict__ lam,
    float* __restrict__ ws) {
  __shared__ float sdw[32][25], ssum[32], swin[32], sbin[32], sbdw[32],
      sofs[64], swa[32];
  int t = threadIdx.x;
  if (t < 32) {
    float s = 0.0f;
#pragma unroll
    for (int i = 0; i < 25; ++i) {
      float v = wdw[t * 25 + i];
      sdw[t][i] = v;
      s += v;
    }
    ssum[t] = s;
    swin[t] = win[t];
    sbin[t] = bin[t];
    sbdw[t] = bdw[t];
    swa[t] = wa[t];
  }
  if (t < 64) sofs[t] = wofs[t];
  __syncthreads();

  int idx = blockIdx.x * 256 + t;  // 24 blocks -> 0..6143
  int b = idx / HWN, n = idx % HWN;
  int y = n >> 6, x = n & 63;
  const float* feat = ws + OFF_FEAT + (size_t)b * HWN;

  float f[25];
#pragma unroll
  for (int i = 0; i < 5; ++i) {
    int yy = y - 2 + i;
    yy = yy < 0 ? 0 : (yy > 47 ? 47 : yy);
#pragma unroll
    for (int j = 0; j < 5; ++j) {
      int xx = x - 2 + j;
      xx = xx < 0 ? 0 : (xx > 63 ? 63 : xx);
      f[i * 5 + j] = feat[yy * WD + xx];
    }
  }
  float fv = f[12];
  float o0 = 0.0f, o1 = 0.0f, fa = 0.0f;
  for (int ch = 0; ch < 32; ++ch) {
    float s = 0.0f;
#pragma unroll
    for (int p = 0; p < 25; ++p) s = fmaf(f[p], sdw[ch][p], s);
    float d = fmaf(swin[ch], s, fmaf(sbin[ch], ssum[ch], sbdw[ch]));
    d = fmaxf(d, 0.0f);
    o0 = fmaf(sofs[ch], d, o0);
    o1 = fmaf(sofs[32 + ch], d, o1);
    fa = fmaf(swa[ch], fmaf(swin[ch], fv, sbin[ch]), fa);
  }
  fa += ba[0];
  float ga = 1.0f + lam[0] * fa;
  float ty = tanhf(o0) * (1.0f / 48.0f) * 100.0f;
  float tx = tanhf(o1) * (1.0f / 64.0f) * 100.0f;
  float ry = ((float)y + 0.5f) / 48.0f * 2.0f - 1.0f;
  float rx = ((float)x + 0.5f) / 64.0f * 2.0f - 1.0f;
  float pyn = fminf(fmaxf(ty + ry, -1.0f), 1.0f);
  float pxn = fminf(fmaxf(tx + rx, -1.0f), 1.0f);
  float py = (pyn + 1.0f) * 0.5f * 47.0f;
  float px = (pxn + 1.0f) * 0.5f * 63.0f;
  *(float4*)(ws + OFF_META + (size_t)idx * 4) = make_float4(py, px, ga, 0.0f);
}

// ---------------- windowed logits: corr_raw[b][n][41*41] ------------------
// grid: B*192 (tiles 2y x 8x), 128 thr. 2q x 3s register micro-tiles.
__global__ __launch_bounds__(128) void logits_kernel(float* __restrict__ ws) {
  __shared__ float qs[16][132];
  __shared__ float ks[48][132];
  __shared__ float smeta[48][8];
  int blk = blockIdx.x;
  int b = blk / 192;
  int tile = blk % 192;
  int yb = (tile >> 3) * 2, xb = (tile & 7) * 8;
  int t = threadIdx.x;

  const float* q = ws + OFF_Q + (size_t)b * HWN * CD;
  const float* k = ws + OFF_K + (size_t)b * HWN * CD;
  const float* meta = ws + OFF_META + (size_t)b * HWN * 4;
  float* corrb = ws + OFF_CORR + (size_t)b * HWN * KKP;

#pragma unroll
  for (int i = 0; i < 4; ++i) {
    int ch = t + 128 * i;  // 512 chunks
    int qq = ch >> 5, c4 = ch & 31;
    int nq = (yb + (qq >> 3)) * WD + xb + (qq & 7);
    *(float4*)&qs[qq][c4 * 4] = *(const float4*)(q + (size_t)nq * CD + c4 * 4);
  }

  int sg = t & 15, qg = t >> 4;
  int q0 = qg * 2, q1 = q0 + 1;
  int ny0 = yb + (q0 >> 3), nx0 = xb + (q0 & 7);
  int ny1 = yb + (q1 >> 3), nx1 = xb + (q1 & 7);
  float* crow0 = corrb + (size_t)(ny0 * WD + nx0) * KKP;
  float* crow1 = corrb + (size_t)(ny1 * WD + nx1) * KKP;

  for (int sy = yb - RAD; sy <= yb + 1 + RAD; ++sy) {
    bool rowOK = (sy >= 0 && sy < HH);
    __syncthreads();
    if (rowOK) {
#pragma unroll
      for (int i = 0; i < 12; ++i) {
        int ch = t + 128 * i;  // 1536 chunks
        int s = ch >> 5, c4 = ch & 31;
        int sx = xb - RAD + s;
        if (sx >= 0 && sx < WD)
          *(float4*)&ks[s][c4 * 4] =
              *(const float4*)(k + (size_t)(sy * WD + sx) * CD + c4 * 4);
      }
      if (t < 48) {
        int s = t, sx = xb - RAD + s;
        if (sx >= 0 && sx < WD) {
          float4 mt = *(const float4*)(meta + (size_t)(sy * WD + sx) * 4);
          float y0f = floorf(mt.x), x0f = floorf(mt.y);
          smeta[s][0] = y0f;
          smeta[s][1] = fminf(y0f + 1.0f, 47.0f);
          smeta[s][2] = mt.x - y0f;
          smeta[s][3] = x0f;
          smeta[s][4] = fminf(x0f + 1.0f, 63.0f);
          smeta[s][5] = mt.y - x0f;
          smeta[s][6] = mt.z;  // ga
          smeta[s][7] = 1.0f;
        } else {
          smeta[s][7] = 0.0f;
        }
      }
    }
    __syncthreads();

    float a00 = 0, a01 = 0, a02 = 0, a10 = 0, a11 = 0, a12 = 0;
    if (rowOK) {
      for (int c4 = 0; c4 < 32; ++c4) {
        float4 qa = *(const float4*)&qs[q0][c4 * 4];
        float4 qb = *(const float4*)&qs[q1][c4 * 4];
        float4 k0 = *(const float4*)&ks[sg][c4 * 4];
        float4 k1 = *(const float4*)&ks[sg + 16][c4 * 4];
        float4 k2 = *(const float4*)&ks[sg + 32][c4 * 4];
        a00 = dot4(qa, k0, a00);
        a01 = dot4(qa, k1, a01);
        a02 = dot4(qa, k2, a02);
        a10 = dot4(qb, k0, a10);
        a11 = dot4(qb, k1, a11);
        a12 = dot4(qb, k2, a12);
      }
    }
    float accs0[3] = {a00, a01, a02};
    float accs1[3] = {a10, a11, a12};

    int dy0 = sy - ny0, dy1 = sy - ny1;
    if (dy0 >= -RAD && dy0 <= RAD) {
      float* crow = crow0 + (dy0 + RAD) * KWIN;
#pragma unroll
      for (int j = 0; j < 3; ++j) {
        int s = sg + 16 * j;
        int dx = (xb - RAD + s) - nx0;
        if (dx < -RAD || dx > RAD) continue;
        float val = 0.0f;
        if (rowOK && smeta[s][7] > 0.0f)
          val = accs0[j] * bilin_g(smeta[s], (float)ny0, (float)nx0) * smeta[s][6];
        crow[dx + RAD] = val;
      }
    }
    if (dy1 >= -RAD && dy1 <= RAD) {
      float* crow = crow1 + (dy1 + RAD) * KWIN;
#pragma unroll
      for (int j = 0; j < 3; ++j) {
        int s = sg + 16 * j;
        int dx = (xb - RAD + s) - nx1;
        if (dx < -RAD || dx > RAD) continue;
        float val = 0.0f;
        if (rowOK && smeta[s][7] > 0.0f)
          val = accs1[j] * bilin_g(smeta[s], (float)ny1, (float)nx1) * smeta[s][6];
        crow[dx + RAD] = val;
      }
    }
  }
}

// ---------------- per-query softmax stats: max, 1/sum ---------------------
__global__ __launch_bounds__(128) void stats_kernel(float* __restrict__ ws) {
  int row = blockIdx.x;  // 0..6143
  const float* base = ws + OFF_CORR + (size_t)row * KKP;
  int t = threadIdx.x;
  float4 f[4];
  int cnt = 0;
  float mx = -1e30f;
  for (int i = t; i < 421; i += 128) {
    float4 v = *(const float4*)(base + (size_t)i * 4);
    if (i == 420) { v.y = -1e30f; v.z = -1e30f; v.w = -1e30f; }
    f[cnt++] = v;
    mx = fmaxf(mx, fmaxf(fmaxf(v.x, v.y), fmaxf(v.z, v.w)));
  }
#pragma unroll
  for (int off = 1; off < 64; off <<= 1) mx = fmaxf(mx, __shfl_xor(mx, off));
  __shared__ float sm[2], ss[2];
  if ((t & 63) == 0) sm[t >> 6] = mx;
  __syncthreads();
  mx = fmaxf(sm[0], sm[1]);
  float sum = 0.0f;
  for (int ci = 0; ci < cnt; ++ci) {
    float4 v = f[ci];
    sum += __expf(v.x - mx) + __expf(v.y - mx) + __expf(v.z - mx) + __expf(v.w - mx);
  }
#pragma unroll
  for (int off = 1; off < 64; off <<= 1) sum += __shfl_xor(sum, off);
  if ((t & 63) == 0) ss[t >> 6] = sum;
  __syncthreads();
  if (t == 0) {
    float tot = ss[0] + ss[1];
    *(float2*)(ws + OFF_STATS + (size_t)row * 2) = make_float2(mx, 1.0f / tot);
  }
}

// ---------------- gather aggregation + residual ---------------------------
// fo[c][n] = sum_{m in win(n)} softmax_m(slot of n) * fv[c][m]
__global__ __launch_bounds__(128) void agg_kernel(
    const float* __restrict__ fmo, const float* __restrict__ gamma,
    float* __restrict__ ws, float* __restrict__ out) {
  __shared__ float fvs[48][132];
  __shared__ float Wsh[48][18];
  int blk = blockIdx.x;
  int b = blk / 192;
  int tile = blk % 192;
  int yb = (tile >> 3) * 2, xb = (tile & 7) * 8;
  int t = threadIdx.x;
  int nl = t & 7, cg = t >> 3;  // nl: output pair, cg: 8-channel group

  const float* v = ws + OFF_V + (size_t)b * HWN * CD;
  const float* corrb = ws + OFF_CORR + (size_t)b * HWN * KKP;
  const float* stats = ws + OFF_STATS + (size_t)b * HWN * 2;

  float accA[8], accB[8];
#pragma unroll
  for (int i = 0; i < 8; ++i) { accA[i] = 0.0f; accB[i] = 0.0f; }

  for (int sy = yb - RAD; sy <= yb + 1 + RAD; ++sy) {
    if (sy < 0 || sy >= HH) continue;  // uniform across block
    __syncthreads();
#pragma unroll
    for (int i = 0; i < 12; ++i) {
      int ch = t + 128 * i;
      int s = ch >> 5, c4 = ch & 31;
      int sx = xb - RAD + s;
      float4 val = make_float4(0.0f, 0.0f, 0.0f, 0.0f);
      if (sx >= 0 && sx < WD)
        val = *(const float4*)(v + (size_t)(sy * WD + sx) * CD + c4 * 4);
      *(float4*)&fvs[s][c4 * 4] = val;
    }
#pragma unroll
    for (int i = 0; i < 6; ++i) {
      int idx = t + 128 * i;  // 768 = 48 sources x 16 outputs
      int s = idx >> 4, o = idx & 15;
      int sx = xb - RAD + s;
      int ny = yb + (o >> 3), nx = xb + (o & 7);
      int ddy = ny - sy, ddx = nx - sx;
      float wv = 0.0f;
      if (sx >= 0 && sx < WD && ddy >= -RAD && ddy <= RAD && ddx >= -RAD &&
          ddx <= RAD) {
        int m = sy * WD + sx;
        float raw = corrb[(size_t)m * KKP + (ddy + RAD) * KWIN + (ddx + RAD)];
        float2 st = *(const float2*)(stats + (size_t)m * 2);
        wv = __expf(raw - st.x) * st.y;
      }
      Wsh[s][o] = wv;
    }
    __syncthreads();

    for (int s = 0; s < 48; ++s) {
      float4 fa4 = *(const float4*)&fvs[s][cg * 8];
      float4 fb4 = *(const float4*)&fvs[s][cg * 8 + 4];
      float2 wp = *(const float2*)&Wsh[s][nl * 2];
      accA[0] = fmaf(wp.x, fa4.x, accA[0]);
      accA[1] = fmaf(wp.x, fa4.y, accA[1]);
      accA[2] = fmaf(wp.x, fa4.z, accA[2]);
      accA[3] = fmaf(wp.x, fa4.w, accA[3]);
      accA[4] = fmaf(wp.x, fb4.x, accA[4]);
      accA[5] = fmaf(wp.x, fb4.y, accA[5]);
      accA[6] = fmaf(wp.x, fb4.z, accA[6]);
      accA[7] = fmaf(wp.x, fb4.w, accA[7]);
      accB[0] = fmaf(wp.y, fa4.x, accB[0]);
      accB[1] = fmaf(wp.y, fa4.y, accB[1]);
      accB[2] = fmaf(wp.y, fa4.z, accB[2]);
      accB[3] = fmaf(wp.y, fa4.w, accB[3]);
      accB[4] = fmaf(wp.y, fb4.x, accB[4]);
      accB[5] = fmaf(wp.y, fb4.y, accB[5]);
      accB[6] = fmaf(wp.y, fb4.z, accB[6]);
      accB[7] = fmaf(wp.y, fb4.w, accB[7]);
    }
  }

  float gm = gamma[0];
#pragma unroll
  for (int p = 0; p < 2; ++p) {
    int o = nl * 2 + p;
    int n = (yb + (o >> 3)) * WD + xb + (o & 7);
    const float* acc = p ? accB : accA;
#pragma unroll
    for (int cc = 0; cc < 8; ++cc) {
      int c = cg * 8 + cc;
      size_t oi = ((size_t)b * CD + c) * HWN + n;
      out[oi] = fmo[oi] + gm * acc[cc];
    }
  }
}

extern "C" void kernel_launch(void* const* d_in, const int* in_sizes, int n_in,
                              void* d_out, int out_size, void* d_ws,
                              size_t ws_size, hipStream_t stream) {
  (void)in_sizes; (void)n_in; (void)out_size; (void)ws_size;
  const float* fctx = (const float*)d_in[0];
  const float* fmo  = (const float*)d_in[1];
  // d_in[2] = itr (int32) -- itr==0 path only
  const float* wqk  = (const float*)d_in[3];
  const float* wv   = (const float*)d_in[4];
  const float* gamma = (const float*)d_in[5];
  const float* win  = (const float*)d_in[6];
  const float* bin  = (const float*)d_in[7];
  const float* wdw  = (const float*)d_in[8];
  const float* bdw  = (const float*)d_in[9];
  const float* wofs = (const float*)d_in[10];
  const float* wa   = (const float*)d_in[11];
  const float* ba   = (const float*)d_in[12];
  const float* lam  = (const float*)d_in[13];
  float* ws = (float*)d_ws;
  float* out = (float*)d_out;

  mean_kernel<<<dim3(96), dim3(256), 0, stream>>>(fmo, ws);
  dgm_kernel<<<dim3(24), dim3(256), 0, stream>>>(win, bin, wdw, bdw, wofs, wa,
                                                 ba, lam, ws);
  qkv_kernel<<<dim3(384), dim3(256), 0, stream>>>(fctx, fmo, wqk, wv, ws);
  logits_kernel<<<dim3(384), dim3(128), 0, stream>>>(ws);
  stats_kernel<<<dim3(6144), dim3(128), 0, stream>>>(ws);
  agg_kernel<<<dim3(384), dim3(128), 0, stream>>>(fmo, gamma, ws, out);
}

// Round 3
// 345.616 us; speedup vs baseline: 2.1131x; 2.1131x over previous
//
#include <hip/hip_runtime.h>
#include <math.h>

// GGAM: windowed (41x41) gaussian-guided attention, b=2 c=128 h=48 w=64.
// v2: sy-parallel logits (5376 blocks), sy-chunked agg with fp32 partials +
// reduce, corr stored fp16, qkv split for occupancy. fp32 math everywhere.

namespace {
constexpr int BB   = 2;
constexpr int CD   = 128;
constexpr int HH   = 48;
constexpr int WD   = 64;
constexpr int HWN  = 3072;
constexpr int KWIN = 41;
constexpr int RAD  = 20;
constexpr int KKPH = 1688;  // fp16 row stride (halves), 16B-divisible rows

constexpr int LCHUNK = 3;   // logits rows per block
constexpr int NLCH   = 14;  // 42 rows total
constexpr int ACHUNK = 7;   // agg rows per block
constexpr int NACH   = 6;   // 42 rows total

// workspace layout (float indices)
constexpr size_t OFF_CORR  = 0;                                  // fp16!
constexpr size_t SZ_CORR   = (size_t)BB * HWN * KKPH / 2;        // 5,185,536 f
constexpr size_t OFF_Q     = OFF_CORR + SZ_CORR;
constexpr size_t OFF_K     = OFF_Q + (size_t)BB * HWN * CD;
constexpr size_t OFF_V     = OFF_K + (size_t)BB * HWN * CD;
constexpr size_t OFF_FEAT  = OFF_V + (size_t)BB * HWN * CD;
constexpr size_t OFF_META  = OFF_FEAT + (size_t)BB * HWN;        // float4/px
constexpr size_t OFF_STATS = OFF_META + (size_t)BB * HWN * 4;    // float2/q
constexpr size_t OFF_PART  = OFF_STATS + (size_t)BB * HWN * 2;   // 6 x 786432
} // namespace

typedef _Float16 h8v __attribute__((ext_vector_type(8)));

__device__ __forceinline__ float dot4(float4 a, float4 b, float acc) {
  return fmaf(a.x, b.x, fmaf(a.y, b.y, fmaf(a.z, b.z, fmaf(a.w, b.w, acc))));
}

// thresholded gaussian: exp(-r2/800)*2.5+10, zero when r2 > 1842 (exact
// integer-r2 decision, matches reference's g < BI+THR*SC_G).
__device__ __forceinline__ float gthr(float dy, float dx) {
  float r2 = fmaf(dy, dy, dx * dx);
  float g  = fmaf(__expf(r2 * (-1.0f / 800.0f)), 2.5f, 10.0f);
  return (r2 <= 1842.0f) ? g : 0.0f;
}

__device__ __forceinline__ float bilin_g(const float* mt, float ny, float nx) {
  float y0 = mt[0], y1 = mt[1], fy = mt[2];
  float x0 = mt[3], x1 = mt[4], fx = mt[5];
  float g00 = gthr(y0 - ny, x0 - nx);
  float g01 = gthr(y0 - ny, x1 - nx);
  float g10 = gthr(y1 - ny, x0 - nx);
  float g11 = gthr(y1 - ny, x1 - nx);
  float top = (1.0f - fx) * g00 + fx * g01;
  float bot = (1.0f - fx) * g10 + fx * g11;
  return (1.0f - fy) * top + fy * bot;
}

// ---------------- qkv: q(scaled)/k = w_qk @ feat_ctx, v = w_v @ feat_mo ----
// grid: B*192*2 = 768 blocks, 256 thr. Block: 16 spatial cols, 192 out rows.
__global__ __launch_bounds__(256) void qkv_kernel(
    const float* __restrict__ fctx, const float* __restrict__ fmo,
    const float* __restrict__ wqk, const float* __restrict__ wv,
    float* __restrict__ ws) {
  __shared__ float xc[128][16];
  __shared__ float xm[128][16];
  int blk = blockIdx.x;
  int b = blk / 384;
  int rem = blk % 384;
  int tile = rem >> 1;
  int half = rem & 1;
  int n0 = tile * 16;
  int t = threadIdx.x;

#pragma unroll
  for (int i = 0; i < 2; ++i) {
    int chunk = t + 256 * i;
    int c = chunk >> 2, nc = chunk & 3;
    *(float4*)&xc[c][nc * 4] =
        *(const float4*)(fctx + ((size_t)b * CD + c) * HWN + n0 + nc * 4);
  }
  if (half) {
#pragma unroll
    for (int i = 0; i < 2; ++i) {
      int chunk = t + 256 * i;
      int c = chunk >> 2, nc = chunk & 3;
      *(float4*)&xm[c][nc * 4] =
          *(const float4*)(fmo + ((size_t)b * CD + c) * HWN + n0 + nc * 4);
    }
  }
  __syncthreads();

  int ng = t & 3, og = t >> 2;  // og 0..63
  const float* wrow[3];
  bool useM[3];
#pragma unroll
  for (int j = 0; j < 3; ++j) {
    int r = half * 192 + og + 64 * j;
    if (r < 256) { wrow[j] = wqk + (size_t)r * CD; useM[j] = false; }
    else         { wrow[j] = wv + (size_t)(r - 256) * CD; useM[j] = true; }
  }
  float acc[3][4];
#pragma unroll
  for (int j = 0; j < 3; ++j)
#pragma unroll
    for (int nn = 0; nn < 4; ++nn) acc[j][nn] = 0.0f;

  for (int c4 = 0; c4 < 32; ++c4) {
    float4 xa0 = *(const float4*)&xc[c4 * 4 + 0][ng * 4];
    float4 xa1 = *(const float4*)&xc[c4 * 4 + 1][ng * 4];
    float4 xa2 = *(const float4*)&xc[c4 * 4 + 2][ng * 4];
    float4 xa3 = *(const float4*)&xc[c4 * 4 + 3][ng * 4];
    float4 xm0, xm1, xm2, xm3;
    if (half) {
      xm0 = *(const float4*)&xm[c4 * 4 + 0][ng * 4];
      xm1 = *(const float4*)&xm[c4 * 4 + 1][ng * 4];
      xm2 = *(const float4*)&xm[c4 * 4 + 2][ng * 4];
      xm3 = *(const float4*)&xm[c4 * 4 + 3][ng * 4];
    }
#pragma unroll
    for (int j = 0; j < 3; ++j) {
      float4 w4 = *(const float4*)(wrow[j] + c4 * 4);
      float4 x0 = (half && useM[j]) ? xm0 : xa0;
      float4 x1 = (half && useM[j]) ? xm1 : xa1;
      float4 x2 = (half && useM[j]) ? xm2 : xa2;
      float4 x3 = (half && useM[j]) ? xm3 : xa3;
      acc[j][0] = fmaf(w4.x, x0.x, fmaf(w4.y, x1.x, fmaf(w4.z, x2.x, fmaf(w4.w, x3.x, acc[j][0]))));
      acc[j][1] = fmaf(w4.x, x0.y, fmaf(w4.y, x1.y, fmaf(w4.z, x2.y, fmaf(w4.w, x3.y, acc[j][1]))));
      acc[j][2] = fmaf(w4.x, x0.z, fmaf(w4.y, x1.z, fmaf(w4.z, x2.z, fmaf(w4.w, x3.z, acc[j][2]))));
      acc[j][3] = fmaf(w4.x, x0.w, fmaf(w4.y, x1.w, fmaf(w4.z, x2.w, fmaf(w4.w, x3.w, acc[j][3]))));
    }
  }

  const float qscale = 0.08838834764831845f;  // 128^-0.5
#pragma unroll
  for (int j = 0; j < 3; ++j) {
    int r = half * 192 + og + 64 * j;
    float* dst;
    float mul = 1.0f;
    int rr;
    if (r < 128)      { dst = ws + OFF_Q; rr = r;       mul = qscale; }
    else if (r < 256) { dst = ws + OFF_K; rr = r - 128; }
    else              { dst = ws + OFF_V; rr = r - 256; }
    size_t nbase = (size_t)b * HWN + n0 + ng * 4;
#pragma unroll
    for (int nn = 0; nn < 4; ++nn)
      dst[(nbase + nn) * CD + rr] = acc[j][nn] * mul;
  }
}

// ---------------- channel mean of feat_mo -> feat[b][n] -------------------
__global__ __launch_bounds__(256) void mean_kernel(
    const float* __restrict__ fmo, float* __restrict__ ws) {
  __shared__ float red[4][64];
  int t = threadIdx.x;
  int nl = t & 63, cgp = t >> 6;
  int p = blockIdx.x * 64 + nl;
  const float* src = fmo + (size_t)(p / HWN) * CD * HWN + (p % HWN);
  float s = 0.0f;
  for (int c = cgp * 32; c < cgp * 32 + 32; ++c) s += src[(size_t)c * HWN];
  red[cgp][nl] = s;
  __syncthreads();
  if (cgp == 0) {
    float tot = red[0][nl] + red[1][nl] + red[2][nl] + red[3][nl];
    ws[OFF_FEAT + p] = tot * (1.0f / 128.0f);
  }
}

// ---------------- DGM: depthwise conv -> offsets -> (py,px,ga) meta -------
__global__ __launch_bounds__(256) void dgm_kernel(
    const float* __restrict__ win, const float* __restrict__ bin,
    const float* __restrict__ wdw, const float* __restrict__ bdw,
    const float* __restrict__ wofs, const float* __restrict__ wa,
    const float* __restrict__ ba, const float* __restrict__ lam,
    float* __restrict__ ws) {
  __shared__ float sdw[32][25], ssum[32], swin[32], sbin[32], sbdw[32],
      sofs[64], swa[32];
  int t = threadIdx.x;
  if (t < 32) {
    float s = 0.0f;
#pragma unroll
    for (int i = 0; i < 25; ++i) {
      float v = wdw[t * 25 + i];
      sdw[t][i] = v;
      s += v;
    }
    ssum[t] = s;
    swin[t] = win[t];
    sbin[t] = bin[t];
    sbdw[t] = bdw[t];
    swa[t] = wa[t];
  }
  if (t < 64) sofs[t] = wofs[t];
  __syncthreads();

  int idx = blockIdx.x * 256 + t;
  int b = idx / HWN, n = idx % HWN;
  int y = n >> 6, x = n & 63;
  const float* feat = ws + OFF_FEAT + (size_t)b * HWN;

  float f[25];
#pragma unroll
  for (int i = 0; i < 5; ++i) {
    int yy = y - 2 + i;
    yy = yy < 0 ? 0 : (yy > 47 ? 47 : yy);
#pragma unroll
    for (int j = 0; j < 5; ++j) {
      int xx = x - 2 + j;
      xx = xx < 0 ? 0 : (xx > 63 ? 63 : xx);
      f[i * 5 + j] = feat[yy * WD + xx];
    }
  }
  float fv = f[12];
  float o0 = 0.0f, o1 = 0.0f, fa = 0.0f;
  for (int ch = 0; ch < 32; ++ch) {
    float s = 0.0f;
#pragma unroll
    for (int p = 0; p < 25; ++p) s = fmaf(f[p], sdw[ch][p], s);
    float d = fmaf(swin[ch], s, fmaf(sbin[ch], ssum[ch], sbdw[ch]));
    d = fmaxf(d, 0.0f);
    o0 = fmaf(sofs[ch], d, o0);
    o1 = fmaf(sofs[32 + ch], d, o1);
    fa = fmaf(swa[ch], fmaf(swin[ch], fv, sbin[ch]), fa);
  }
  fa += ba[0];
  float ga = 1.0f + lam[0] * fa;
  float ty = tanhf(o0) * (1.0f / 48.0f) * 100.0f;
  float tx = tanhf(o1) * (1.0f / 64.0f) * 100.0f;
  float ry = ((float)y + 0.5f) / 48.0f * 2.0f - 1.0f;
  float rx = ((float)x + 0.5f) / 64.0f * 2.0f - 1.0f;
  float pyn = fminf(fmaxf(ty + ry, -1.0f), 1.0f);
  float pxn = fminf(fmaxf(tx + rx, -1.0f), 1.0f);
  float py = (pyn + 1.0f) * 0.5f * 47.0f;
  float px = (pxn + 1.0f) * 0.5f * 63.0f;
  *(float4*)(ws + OFF_META + (size_t)idx * 4) = make_float4(py, px, ga, 0.0f);
}

// ---------------- windowed logits (fp16 out): corr[b][n][41*41] -----------
// grid: B*192 tiles * 14 sy-chunks = 5376 blocks, 128 thr (2q x 3s tiles).
__global__ __launch_bounds__(128) void logits_kernel(float* __restrict__ ws) {
  __shared__ float qs[16][132];
  __shared__ float ks[48][132];
  __shared__ float smeta[48][8];
  int blk = blockIdx.x;
  int b = blk / (192 * NLCH);
  int rem = blk % (192 * NLCH);
  int tile = rem / NLCH;
  int chunk = rem % NLCH;
  int yb = (tile >> 3) * 2, xb = (tile & 7) * 8;
  int t = threadIdx.x;

  const float* q = ws + OFF_Q + (size_t)b * HWN * CD;
  const float* k = ws + OFF_K + (size_t)b * HWN * CD;
  const float* meta = ws + OFF_META + (size_t)b * HWN * 4;
  _Float16* corrH = (_Float16*)(ws + OFF_CORR) + (size_t)b * HWN * KKPH;

#pragma unroll
  for (int i = 0; i < 4; ++i) {
    int ch = t + 128 * i;  // 512 chunks
    int qq = ch >> 5, c4 = ch & 31;
    int nq = (yb + (qq >> 3)) * WD + xb + (qq & 7);
    *(float4*)&qs[qq][c4 * 4] = *(const float4*)(q + (size_t)nq * CD + c4 * 4);
  }

  int sg = t & 15, qg = t >> 4;
  int q0 = qg * 2, q1 = q0 + 1;
  int ny0 = yb + (q0 >> 3), nx0 = xb + (q0 & 7);
  int ny1 = yb + (q1 >> 3), nx1 = xb + (q1 & 7);
  _Float16* crow0 = corrH + (size_t)(ny0 * WD + nx0) * KKPH;
  _Float16* crow1 = corrH + (size_t)(ny1 * WD + nx1) * KKPH;

  int sy0 = yb - RAD + chunk * LCHUNK;
  for (int sy = sy0; sy < sy0 + LCHUNK; ++sy) {
    bool rowOK = (sy >= 0 && sy < HH);
    __syncthreads();
    if (rowOK) {
#pragma unroll
      for (int i = 0; i < 12; ++i) {
        int ch = t + 128 * i;  // 1536 chunks
        int s = ch >> 5, c4 = ch & 31;
        int sx = xb - RAD + s;
        if (sx >= 0 && sx < WD)
          *(float4*)&ks[s][c4 * 4] =
              *(const float4*)(k + (size_t)(sy * WD + sx) * CD + c4 * 4);
      }
      if (t < 48) {
        int s = t, sx = xb - RAD + s;
        if (sx >= 0 && sx < WD) {
          float4 mt = *(const float4*)(meta + (size_t)(sy * WD + sx) * 4);
          float y0f = floorf(mt.x), x0f = floorf(mt.y);
          smeta[s][0] = y0f;
          smeta[s][1] = fminf(y0f + 1.0f, 47.0f);
          smeta[s][2] = mt.x - y0f;
          smeta[s][3] = x0f;
          smeta[s][4] = fminf(x0f + 1.0f, 63.0f);
          smeta[s][5] = mt.y - x0f;
          smeta[s][6] = mt.z;  // ga
          smeta[s][7] = 1.0f;
        } else {
          smeta[s][7] = 0.0f;
        }
      }
    }
    __syncthreads();

    float a00 = 0, a01 = 0, a02 = 0, a10 = 0, a11 = 0, a12 = 0;
    if (rowOK) {
      for (int c4 = 0; c4 < 32; ++c4) {
        float4 qa = *(const float4*)&qs[q0][c4 * 4];
        float4 qb = *(const float4*)&qs[q1][c4 * 4];
        float4 k0 = *(const float4*)&ks[sg][c4 * 4];
        float4 k1 = *(const float4*)&ks[sg + 16][c4 * 4];
        float4 k2 = *(const float4*)&ks[sg + 32][c4 * 4];
        a00 = dot4(qa, k0, a00);
        a01 = dot4(qa, k1, a01);
        a02 = dot4(qa, k2, a02);
        a10 = dot4(qb, k0, a10);
        a11 = dot4(qb, k1, a11);
        a12 = dot4(qb, k2, a12);
      }
    }
    float accs0[3] = {a00, a01, a02};
    float accs1[3] = {a10, a11, a12};

    int dy0 = sy - ny0, dy1 = sy - ny1;
    if (dy0 >= -RAD && dy0 <= RAD) {
      _Float16* crow = crow0 + (dy0 + RAD) * KWIN;
#pragma unroll
      for (int j = 0; j < 3; ++j) {
        int s = sg + 16 * j;
        int dx = (xb - RAD + s) - nx0;
        if (dx < -RAD || dx > RAD) continue;
        float val = 0.0f;
        if (rowOK && smeta[s][7] > 0.0f)
          val = accs0[j] * bilin_g(smeta[s], (float)ny0, (float)nx0) * smeta[s][6];
        crow[dx + RAD] = (_Float16)val;
      }
    }
    if (dy1 >= -RAD && dy1 <= RAD) {
      _Float16* crow = crow1 + (dy1 + RAD) * KWIN;
#pragma unroll
      for (int j = 0; j < 3; ++j) {
        int s = sg + 16 * j;
        int dx = (xb - RAD + s) - nx1;
        if (dx < -RAD || dx > RAD) continue;
        float val = 0.0f;
        if (rowOK && smeta[s][7] > 0.0f)
          val = accs1[j] * bilin_g(smeta[s], (float)ny1, (float)nx1) * smeta[s][6];
        crow[dx + RAD] = (_Float16)val;
      }
    }
  }
}

// ---------------- per-query softmax stats: max, 1/sum ---------------------
__global__ __launch_bounds__(128) void stats_kernel(float* __restrict__ ws) {
  int row = blockIdx.x;  // 0..6143
  const _Float16* base = (const _Float16*)(ws + OFF_CORR) + (size_t)row * KKPH;
  int t = threadIdx.x;
  float vals[2][8];
  int cis[2];
  int cnt = 0;
  float mx = -1e30f;
  for (int ci = t; ci < 211; ci += 128) {
    h8v hv = *(const h8v*)(base + (size_t)ci * 8);
    int rem = 1681 - ci * 8;  // >=1
#pragma unroll
    for (int j = 0; j < 8; ++j) {
      float fv = (j < rem) ? (float)hv[j] : -1e30f;
      vals[cnt][j] = fv;
      mx = fmaxf(mx, fv);
    }
    cis[cnt] = rem;
    ++cnt;
  }
#pragma unroll
  for (int off = 1; off < 64; off <<= 1) mx = fmaxf(mx, __shfl_xor(mx, off));
  __shared__ float sm[2], ss[2];
  if ((t & 63) == 0) sm[t >> 6] = mx;
  __syncthreads();
  mx = fmaxf(sm[0], sm[1]);
  float sum = 0.0f;
  for (int c = 0; c < cnt; ++c) {
#pragma unroll
    for (int j = 0; j < 8; ++j)
      if (j < cis[c]) sum += __expf(vals[c][j] - mx);
  }
#pragma unroll
  for (int off = 1; off < 64; off <<= 1) sum += __shfl_xor(sum, off);
  if ((t & 63) == 0) ss[t >> 6] = sum;
  __syncthreads();
  if (t == 0) {
    float tot = ss[0] + ss[1];
    *(float2*)(ws + OFF_STATS + (size_t)row * 2) = make_float2(mx, 1.0f / tot);
  }
}

// ---------------- gather aggregation -> fp32 partials ---------------------
// grid: B*192 tiles * 6 chunks = 2304 blocks, 128 thr.
// wave w handles s-half; lane: 4 outputs x 8 channels.
__global__ __launch_bounds__(128) void agg_kernel(float* __restrict__ ws) {
  __shared__ float fvs[48][132];
  __shared__ float Wsh[48][16];
  __shared__ float red2[64][33];
  int blk = blockIdx.x;
  int b = blk / (192 * NACH);
  int rem = blk % (192 * NACH);
  int tile = rem / NACH;
  int chunk = rem % NACH;
  int yb = (tile >> 3) * 2, xb = (tile & 7) * 8;
  int t = threadIdx.x;
  int wv = t >> 6, lane = t & 63;
  int o4 = (lane & 3) * 4;       // 4 outputs o4..o4+3
  int c8 = (lane >> 2) * 8;      // 8 channels

  const float* v = ws + OFF_V + (size_t)b * HWN * CD;
  const _Float16* corrH = (const _Float16*)(ws + OFF_CORR) + (size_t)b * HWN * KKPH;
  const float* stats = ws + OFF_STATS + (size_t)b * HWN * 2;

  float acc[4][8];
#pragma unroll
  for (int i = 0; i < 4; ++i)
#pragma unroll
    for (int j = 0; j < 8; ++j) acc[i][j] = 0.0f;

  int sy0 = yb - RAD + chunk * ACHUNK;
  for (int sy = sy0; sy < sy0 + ACHUNK; ++sy) {
    if (sy < 0 || sy >= HH) continue;  // uniform across block
    __syncthreads();
#pragma unroll
    for (int i = 0; i < 12; ++i) {
      int ch = t + 128 * i;
      int s = ch >> 5, c4 = ch & 31;
      int sx = xb - RAD + s;
      float4 val = make_float4(0.0f, 0.0f, 0.0f, 0.0f);
      if (sx >= 0 && sx < WD)
        val = *(const float4*)(v + (size_t)(sy * WD + sx) * CD + c4 * 4);
      *(float4*)&fvs[s][c4 * 4] = val;
    }
#pragma unroll
    for (int i = 0; i < 6; ++i) {
      int idx = t + 128 * i;  // 768 = 48 src x 16 out
      int s = idx >> 4, o = idx & 15;
      int sx = xb - RAD + s;
      int ny = yb + (o >> 3), nx = xb + (o & 7);
      int ddy = ny - sy, ddx = nx - sx;
      float wval = 0.0f;
      if (sx >= 0 && sx < WD && ddy >= -RAD && ddy <= RAD && ddx >= -RAD &&
          ddx <= RAD) {
        int m = sy * WD + sx;
        float raw = (float)corrH[(size_t)m * KKPH + (ddy + RAD) * KWIN + ddx + RAD];
        float2 st = *(const float2*)(stats + (size_t)m * 2);
        wval = __expf(raw - st.x) * st.y;
      }
      Wsh[s][o] = wval;
    }
    __syncthreads();

    int sbeg = wv * 24;
    for (int s = sbeg; s < sbeg + 24; ++s) {
      float4 w4 = *(const float4*)&Wsh[s][o4];
      float4 fa4 = *(const float4*)&fvs[s][c8];
      float4 fb4 = *(const float4*)&fvs[s][c8 + 4];
      float wq[4] = {w4.x, w4.y, w4.z, w4.w};
#pragma unroll
      for (int oi = 0; oi < 4; ++oi) {
        acc[oi][0] = fmaf(wq[oi], fa4.x, acc[oi][0]);
        acc[oi][1] = fmaf(wq[oi], fa4.y, acc[oi][1]);
        acc[oi][2] = fmaf(wq[oi], fa4.z, acc[oi][2]);
        acc[oi][3] = fmaf(wq[oi], fa4.w, acc[oi][3]);
        acc[oi][4] = fmaf(wq[oi], fb4.x, acc[oi][4]);
        acc[oi][5] = fmaf(wq[oi], fb4.y, acc[oi][5]);
        acc[oi][6] = fmaf(wq[oi], fb4.z, acc[oi][6]);
        acc[oi][7] = fmaf(wq[oi], fb4.w, acc[oi][7]);
      }
    }
  }

  // cross-wave reduce (wave1 -> LDS, wave0 adds) then write partial.
  __syncthreads();
  if (wv == 1) {
#pragma unroll
    for (int oi = 0; oi < 4; ++oi)
#pragma unroll
      for (int cj = 0; cj < 8; ++cj) red2[lane][oi * 8 + cj] = acc[oi][cj];
  }
  __syncthreads();
  if (wv == 0) {
    float* part = ws + OFF_PART + (size_t)(chunk * BB + b) * CD * HWN;
#pragma unroll
    for (int oi = 0; oi < 4; ++oi) {
      int o = o4 + oi;
      int n = (yb + (o >> 3)) * WD + xb + (o & 7);
#pragma unroll
      for (int cj = 0; cj < 8; ++cj) {
        float s = acc[oi][cj] + red2[lane][oi * 8 + cj];
        part[(size_t)(c8 + cj) * HWN + n] = s;
      }
    }
  }
}

// ---------------- reduce partials + residual ------------------------------
__global__ __launch_bounds__(256) void reduce_kernel(
    const float* __restrict__ fmo, const float* __restrict__ gamma,
    const float* __restrict__ ws, float* __restrict__ out) {
  size_t i4 = (size_t)blockIdx.x * 256 + threadIdx.x;  // f4 index, 196608 tot
  const float4* f4 = (const float4*)fmo;
  float4 base = f4[i4];
  float4 s = make_float4(0.0f, 0.0f, 0.0f, 0.0f);
  const float4* part = (const float4*)(ws + OFF_PART);
#pragma unroll
  for (int ch = 0; ch < NACH; ++ch) {
    float4 p = part[(size_t)ch * (BB * CD * HWN / 4) + i4];
    s.x += p.x; s.y += p.y; s.z += p.z; s.w += p.w;
  }
  float gm = gamma[0];
  float4 o;
  o.x = base.x + gm * s.x;
  o.y = base.y + gm * s.y;
  o.z = base.z + gm * s.z;
  o.w = base.w + gm * s.w;
  ((float4*)out)[i4] = o;
}

extern "C" void kernel_launch(void* const* d_in, const int* in_sizes, int n_in,
                              void* d_out, int out_size, void* d_ws,
                              size_t ws_size, hipStream_t stream) {
  (void)in_sizes; (void)n_in; (void)out_size; (void)ws_size;
  const float* fctx = (const float*)d_in[0];
  const float* fmo  = (const float*)d_in[1];
  const float* wqk  = (const float*)d_in[3];
  const float* wvv  = (const float*)d_in[4];
  const float* gamma = (const float*)d_in[5];
  const float* win  = (const float*)d_in[6];
  const float* bin  = (const float*)d_in[7];
  const float* wdw  = (const float*)d_in[8];
  const float* bdw  = (const float*)d_in[9];
  const float* wofs = (const float*)d_in[10];
  const float* wa   = (const float*)d_in[11];
  const float* ba   = (const float*)d_in[12];
  const float* lam  = (const float*)d_in[13];
  float* ws = (float*)d_ws;
  float* out = (float*)d_out;

  mean_kernel<<<dim3(96), dim3(256), 0, stream>>>(fmo, ws);
  dgm_kernel<<<dim3(24), dim3(256), 0, stream>>>(win, bin, wdw, bdw, wofs, wa,
                                                 ba, lam, ws);
  qkv_kernel<<<dim3(768), dim3(256), 0, stream>>>(fctx, fmo, wqk, wvv, ws);
  logits_kernel<<<dim3(BB * 192 * NLCH), dim3(128), 0, stream>>>(ws);
  stats_kernel<<<dim3(6144), dim3(128), 0, stream>>>(ws);
  agg_kernel<<<dim3(BB * 192 * NACH), dim3(128), 0, stream>>>(ws);
  reduce_kernel<<<dim3(768), dim3(256), 0, stream>>>(fmo, gamma, ws, out);
}

// Round 9
// 233.913 us; speedup vs baseline: 3.1222x; 1.4775x over previous
//
#include <hip/hip_runtime.h>
#include <math.h>

// GGAM v4: MFMA (fp16) QK^T logits (v3) + v2-style scalar gather agg with
// the REFERENCE aggregation direction: out[n] = sum_{queries m: n in win(m)}
// softmax_m(slot n) * fv[:, m].  corr layout [tile][42 sy][16 q][48 src]
// fp16, -inf at non-window slots, 0.0 at image-OOB window slots.

namespace {
constexpr int BB   = 2;
constexpr int CD   = 128;
constexpr int HH   = 48;
constexpr int WD   = 64;
constexpr int HWN  = 3072;
constexpr int NACH = 6;     // agg sy chunks (7 rows each)

// workspace layout (float indices)
constexpr size_t OFF_CORR  = 0;                       // fp16 [b*192][42][16][48]
constexpr size_t SZ_CORR   = (size_t)BB*192*42*16*48/2;   // 6,193,152 f
constexpr size_t OFF_Q     = OFF_CORR + SZ_CORR;          // fp16 [b][n][128]
constexpr size_t OFF_K     = OFF_Q + (size_t)BB*HWN*CD/2;
constexpr size_t OFF_V     = OFF_K + (size_t)BB*HWN*CD/2; // fp16 [b][n][128]
constexpr size_t OFF_FEAT  = OFF_V + (size_t)BB*HWN*CD/2;
constexpr size_t OFF_META  = OFF_FEAT + (size_t)BB*HWN;   // float4/px
constexpr size_t OFF_STATS = OFF_META + (size_t)BB*HWN*4; // float2/q
constexpr size_t OFF_PART  = OFF_STATS + (size_t)BB*HWN*2;
} // namespace

typedef _Float16 half8 __attribute__((ext_vector_type(8)));
typedef float f32x4 __attribute__((ext_vector_type(4)));

__device__ __forceinline__ half8 h8zero() {
  half8 z;
#pragma unroll
  for (int e = 0; e < 8; ++e) z[e] = (_Float16)0.0f;
  return z;
}

// ---------------- qkv + channel-mean ---------------------------------------
// grid: B*192*2 = 768 blocks, 256 thr. Block: 16 spatial cols, 192 out rows.
__global__ __launch_bounds__(256) void qkv_kernel(
    const float* __restrict__ fctx, const float* __restrict__ fmo,
    const float* __restrict__ wqk, const float* __restrict__ wv,
    float* __restrict__ ws) {
  __shared__ float xc[128][16];
  __shared__ float xm[128][16];
  int blk = blockIdx.x;
  int b = blk / 384;
  int rem = blk % 384;
  int tile = rem >> 1;
  int half = rem & 1;
  int n0 = tile * 16;
  int t = threadIdx.x;

#pragma unroll
  for (int i = 0; i < 2; ++i) {
    int chunk = t + 256 * i;
    int c = chunk >> 2, nc = chunk & 3;
    *(float4*)&xc[c][nc * 4] =
        *(const float4*)(fctx + ((size_t)b * CD + c) * HWN + n0 + nc * 4);
  }
  if (half) {
#pragma unroll
    for (int i = 0; i < 2; ++i) {
      int chunk = t + 256 * i;
      int c = chunk >> 2, nc = chunk & 3;
      *(float4*)&xm[c][nc * 4] =
          *(const float4*)(fmo + ((size_t)b * CD + c) * HWN + n0 + nc * 4);
    }
  }
  __syncthreads();

  // fused channel-mean (feat) from xm
  if (half && t < 16) {
    float s = 0.0f;
    for (int c = 0; c < 128; ++c) s += xm[c][t];
    ws[OFF_FEAT + (size_t)b * HWN + n0 + t] = s * (1.0f / 128.0f);
  }

  int ng = t & 3, og = t >> 2;  // og 0..63
  const float* wrow[3];
#pragma unroll
  for (int j = 0; j < 3; ++j) {
    int r = half * 192 + og + 64 * j;
    if (r < 256) wrow[j] = wqk + (size_t)r * CD;
    else         wrow[j] = wv + (size_t)(r - 256) * CD;
  }
  bool useM[3];
#pragma unroll
  for (int j = 0; j < 3; ++j) useM[j] = (half * 192 + og + 64 * j) >= 256;

  float acc[3][4];
#pragma unroll
  for (int j = 0; j < 3; ++j)
#pragma unroll
    for (int nn = 0; nn < 4; ++nn) acc[j][nn] = 0.0f;

  for (int c4 = 0; c4 < 32; ++c4) {
    float4 xa0 = *(const float4*)&xc[c4 * 4 + 0][ng * 4];
    float4 xa1 = *(const float4*)&xc[c4 * 4 + 1][ng * 4];
    float4 xa2 = *(const float4*)&xc[c4 * 4 + 2][ng * 4];
    float4 xa3 = *(const float4*)&xc[c4 * 4 + 3][ng * 4];
    float4 xm0, xm1, xm2, xm3;
    if (half) {
      xm0 = *(const float4*)&xm[c4 * 4 + 0][ng * 4];
      xm1 = *(const float4*)&xm[c4 * 4 + 1][ng * 4];
      xm2 = *(const float4*)&xm[c4 * 4 + 2][ng * 4];
      xm3 = *(const float4*)&xm[c4 * 4 + 3][ng * 4];
    }
#pragma unroll
    for (int j = 0; j < 3; ++j) {
      float4 w4 = *(const float4*)(wrow[j] + c4 * 4);
      float4 x0 = (half && useM[j]) ? xm0 : xa0;
      float4 x1 = (half && useM[j]) ? xm1 : xa1;
      float4 x2 = (half && useM[j]) ? xm2 : xa2;
      float4 x3 = (half && useM[j]) ? xm3 : xa3;
      acc[j][0] = fmaf(w4.x, x0.x, fmaf(w4.y, x1.x, fmaf(w4.z, x2.x, fmaf(w4.w, x3.x, acc[j][0]))));
      acc[j][1] = fmaf(w4.x, x0.y, fmaf(w4.y, x1.y, fmaf(w4.z, x2.y, fmaf(w4.w, x3.y, acc[j][1]))));
      acc[j][2] = fmaf(w4.x, x0.z, fmaf(w4.y, x1.z, fmaf(w4.z, x2.z, fmaf(w4.w, x3.z, acc[j][2]))));
      acc[j][3] = fmaf(w4.x, x0.w, fmaf(w4.y, x1.w, fmaf(w4.z, x2.w, fmaf(w4.w, x3.w, acc[j][3]))));
    }
  }

  const float qscale = 0.08838834764831845f;  // 128^-0.5
  _Float16* Qh = (_Float16*)(ws + OFF_Q);
  _Float16* Kh = (_Float16*)(ws + OFF_K);
  _Float16* Vh = (_Float16*)(ws + OFF_V);
#pragma unroll
  for (int j = 0; j < 3; ++j) {
    int r = half * 192 + og + 64 * j;
#pragma unroll
    for (int nn = 0; nn < 4; ++nn) {
      int n = n0 + ng * 4 + nn;
      float v = acc[j][nn];
      if (r < 128)
        Qh[((size_t)b * HWN + n) * CD + r] = (_Float16)(v * qscale);
      else if (r < 256)
        Kh[((size_t)b * HWN + n) * CD + (r - 128)] = (_Float16)v;
      else
        Vh[((size_t)b * HWN + n) * CD + (r - 256)] = (_Float16)v;
    }
  }
}

// ---------------- DGM: depthwise conv -> offsets -> (py,px,ga) meta -------
__global__ __launch_bounds__(256) void dgm_kernel(
    const float* __restrict__ win, const float* __restrict__ bin,
    const float* __restrict__ wdw, const float* __restrict__ bdw,
    const float* __restrict__ wofs, const float* __restrict__ wa,
    const float* __restrict__ ba, const float* __restrict__ lam,
    float* __restrict__ ws) {
  __shared__ float sdw[32][25], ssum[32], swin[32], sbin[32], sbdw[32],
      sofs[64], swa[32];
  int t = threadIdx.x;
  if (t < 32) {
    float s = 0.0f;
#pragma unroll
    for (int i = 0; i < 25; ++i) {
      float v = wdw[t * 25 + i];
      sdw[t][i] = v;
      s += v;
    }
    ssum[t] = s;
    swin[t] = win[t];
    sbin[t] = bin[t];
    sbdw[t] = bdw[t];
    swa[t] = wa[t];
  }
  if (t < 64) sofs[t] = wofs[t];
  __syncthreads();

  int idx = blockIdx.x * 256 + t;
  int b = idx / HWN, n = idx % HWN;
  int y = n >> 6, x = n & 63;
  const float* feat = ws + OFF_FEAT + (size_t)b * HWN;

  float f[25];
#pragma unroll
  for (int i = 0; i < 5; ++i) {
    int yy = y - 2 + i;
    yy = yy < 0 ? 0 : (yy > 47 ? 47 : yy);
#pragma unroll
    for (int j = 0; j < 5; ++j) {
      int xx = x - 2 + j;
      xx = xx < 0 ? 0 : (xx > 63 ? 63 : xx);
      f[i * 5 + j] = feat[yy * WD + xx];
    }
  }
  float fv = f[12];
  float o0 = 0.0f, o1 = 0.0f, fa = 0.0f;
  for (int ch = 0; ch < 32; ++ch) {
    float s = 0.0f;
#pragma unroll
    for (int p = 0; p < 25; ++p) s = fmaf(f[p], sdw[ch][p], s);
    float d = fmaf(swin[ch], s, fmaf(sbin[ch], ssum[ch], sbdw[ch]));
    d = fmaxf(d, 0.0f);
    o0 = fmaf(sofs[ch], d, o0);
    o1 = fmaf(sofs[32 + ch], d, o1);
    fa = fmaf(swa[ch], fmaf(swin[ch], fv, sbin[ch]), fa);
  }
  fa += ba[0];
  float ga = 1.0f + lam[0] * fa;
  float ty = tanhf(o0) * (1.0f / 48.0f) * 100.0f;
  float tx = tanhf(o1) * (1.0f / 64.0f) * 100.0f;
  float ry = ((float)y + 0.5f) / 48.0f * 2.0f - 1.0f;
  float rx = ((float)x + 0.5f) / 64.0f * 2.0f - 1.0f;
  float pyn = fminf(fmaxf(ty + ry, -1.0f), 1.0f);
  float pxn = fminf(fmaxf(tx + rx, -1.0f), 1.0f);
  float py = (pyn + 1.0f) * 0.5f * 47.0f;
  float px = (pxn + 1.0f) * 0.5f * 63.0f;
  *(float4*)(ws + OFF_META + (size_t)idx * 4) = make_float4(py, px, ga, 0.0f);
}

// ---------------- logits via MFMA: corr[tile][slot][q][48] fp16 -----------
// grid: B*192*42 = 16128 blocks, 64 thr (one wave, one sy row of one tile).
__global__ __launch_bounds__(64) void logits_kernel(float* __restrict__ ws) {
  int blk = blockIdx.x;
  int b = blk / (192 * 42);
  int rem = blk % (192 * 42);
  int tile = rem / 42;
  int slot = rem % 42;
  int yb = (tile >> 3) * 2, xb = (tile & 7) * 8;
  int sy = yb - 20 + slot;
  int l = threadIdx.x;
  int g = l >> 4, ln = l & 15;

  const _Float16* Qh = (const _Float16*)(ws + OFF_Q) + (size_t)b * HWN * CD;
  const _Float16* Kh = (const _Float16*)(ws + OFF_K) + (size_t)b * HWN * CD;
  const float* meta = ws + OFF_META + (size_t)b * HWN * 4;
  _Float16* corr = (_Float16*)(ws + OFF_CORR) +
                   (((size_t)(b * 192 + tile)) * 42 + slot) * 768;

  // A-frags: query row = ln, k(ch) = 32*s + 8*g + j
  int nq = (yb + (ln >> 3)) * WD + xb + (ln & 7);
  half8 qf[4];
#pragma unroll
  for (int s = 0; s < 4; ++s)
    qf[s] = *(const half8*)(Qh + (size_t)nq * CD + s * 32 + g * 8);

  bool rowOK = (sy >= 0 && sy < HH);
  int ny = yb + (g >> 1);           // = yb + (row>>3) for rows 4g..4g+3
  int dyi = sy - ny;
  bool dyok = (dyi >= -20 && dyi <= 20);

  for (int st = 0; st < 3; ++st) {
    int sx = xb - 20 + st * 16 + ln;
    f32x4 acc = {0.0f, 0.0f, 0.0f, 0.0f};
    float py = 0.0f, px = 0.0f, ga = 0.0f;
    if (rowOK) {
      int sxc = sx < 0 ? 0 : (sx > 63 ? 63 : sx);
      size_t ms = (size_t)(sy * WD + sxc);
#pragma unroll
      for (int s = 0; s < 4; ++s) {
        half8 bf = *(const half8*)(Kh + ms * CD + s * 32 + g * 8);
        acc = __builtin_amdgcn_mfma_f32_16x16x32_f16(qf[s], bf, acc, 0, 0, 0);
      }
      float4 mt = *(const float4*)(meta + ms * 4);
      py = mt.x; px = mt.y; ga = mt.z;
    }

    bool imgok = rowOK && (sx >= 0 && sx < 64);
    float y0f = 0, y1f = 0, fy = 0, x0f = 0, x1f = 0, fx = 0;
    float ey0 = 0, ey1 = 0, dy20 = 0, dy21 = 0;
    if (imgok) {
      y0f = floorf(py); y1f = fminf(y0f + 1.0f, 47.0f); fy = py - y0f;
      x0f = floorf(px); x1f = fminf(x0f + 1.0f, 63.0f); fx = px - x0f;
      float d0 = y0f - (float)ny, d1 = y1f - (float)ny;
      dy20 = d0 * d0; dy21 = d1 * d1;
      ey0 = __expf(dy20 * (-1.0f / 800.0f));
      ey1 = __expf(dy21 * (-1.0f / 800.0f));
    }
#pragma unroll
    for (int r = 0; r < 4; ++r) {
      int row = 4 * g + r;
      int nx = xb + (row & 7);
      int dx = sx - nx;
      bool win = dyok && dx >= -20 && dx <= 20;
      float val;
      if (!win) {
        val = -INFINITY;
      } else if (!imgok) {
        val = 0.0f;
      } else {
        float dx0 = x0f - (float)nx, dx1 = x1f - (float)nx;
        float dx20 = dx0 * dx0, dx21 = dx1 * dx1;
        float ex0 = __expf(dx20 * (-1.0f / 800.0f));
        float ex1 = __expf(dx21 * (-1.0f / 800.0f));
        float g00 = (dy20 + dx20 <= 1842.0f) ? fmaf(2.5f, ey0 * ex0, 10.0f) : 0.0f;
        float g01 = (dy20 + dx21 <= 1842.0f) ? fmaf(2.5f, ey0 * ex1, 10.0f) : 0.0f;
        float g10 = (dy21 + dx20 <= 1842.0f) ? fmaf(2.5f, ey1 * ex0, 10.0f) : 0.0f;
        float g11 = (dy21 + dx21 <= 1842.0f) ? fmaf(2.5f, ey1 * ex1, 10.0f) : 0.0f;
        float top = (1.0f - fx) * g00 + fx * g01;
        float bot = (1.0f - fx) * g10 + fx * g11;
        float gd = (1.0f - fy) * top + fy * bot;
        val = acc[r] * gd * ga;
      }
      corr[row * 48 + st * 16 + ln] = (_Float16)val;
    }
  }
}

// ---------------- per-query softmax stats: max, 1/sum ---------------------
// grid: 1536 blocks x 256 thr (4 waves = 4 queries; lane = sy slot).
__global__ __launch_bounds__(256) void stats_kernel(float* __restrict__ ws) {
  int t = threadIdx.x;
  int wv = t >> 6, lane = t & 63;
  int qg = blockIdx.x * 4 + wv;  // 0..6143
  int b = qg / HWN, n = qg % HWN;
  int y = n >> 6, x = n & 63;
  int tile = (y >> 1) * 8 + (x >> 3);
  int q = (y & 1) * 8 + (x & 7);
  const _Float16* base = (const _Float16*)(ws + OFF_CORR) +
                         ((size_t)(b * 192 + tile) * 42) * 768 + q * 48;
  half8 hv[6];
  float mx = -INFINITY;
  if (lane < 42) {
#pragma unroll
    for (int j = 0; j < 6; ++j) {
      hv[j] = *(const half8*)(base + (size_t)lane * 768 + 8 * j);
#pragma unroll
      for (int e = 0; e < 8; ++e) mx = fmaxf(mx, (float)hv[j][e]);
    }
  }
#pragma unroll
  for (int off = 1; off < 64; off <<= 1) mx = fmaxf(mx, __shfl_xor(mx, off));
  float sum = 0.0f;
  if (lane < 42) {
#pragma unroll
    for (int j = 0; j < 6; ++j)
#pragma unroll
      for (int e = 0; e < 8; ++e) sum += __expf((float)hv[j][e] - mx);
  }
#pragma unroll
  for (int off = 1; off < 64; off <<= 1) sum += __shfl_xor(sum, off);
  if (lane == 0)
    *(float2*)(ws + OFF_STATS + (size_t)qg * 2) = make_float2(mx, 1.0f / sum);
}

// ---------------- gather agg (reference direction) -> fp32 partials -------
// out[n] = sum_{m in win(n)} exp(corr_m[slot n]-mx_m)*inv_m * fv[:, m]
// grid: B*192*NACH = 2304 blocks, 128 thr (2 waves split 48 sources).
__global__ __launch_bounds__(128) void agg_kernel(float* __restrict__ ws) {
  __shared__ _Float16 fvs[48][136];   // fp16 V rows, padded
  __shared__ float Wsh[48][16];
  __shared__ float red2[64][33];
  int blk = blockIdx.x;
  int b = blk / (192 * NACH);
  int rem = blk % (192 * NACH);
  int tile = rem / NACH;
  int chunk = rem % NACH;
  int yb = (tile >> 3) * 2, xb = (tile & 7) * 8;
  int t = threadIdx.x;
  int wv = t >> 6, lane = t & 63;
  int o4 = (lane & 3) * 4;       // 4 outputs
  int c8 = (lane >> 2) * 8;      // 8 channels

  const _Float16* Vh = (const _Float16*)(ws + OFF_V) + (size_t)b * HWN * CD;
  const _Float16* corrB = (const _Float16*)(ws + OFF_CORR) +
                          (size_t)b * 192 * 42 * 768;
  const float* stats = ws + OFF_STATS + (size_t)b * HWN * 2;

  float acc[4][8];
#pragma unroll
  for (int i = 0; i < 4; ++i)
#pragma unroll
    for (int j = 0; j < 8; ++j) acc[i][j] = 0.0f;

  int sy0 = yb - 20 + chunk * 7;
  for (int sy = sy0; sy < sy0 + 7; ++sy) {
    if (sy < 0 || sy >= HH) continue;  // uniform across block
    __syncthreads();
    // stage V (queries m of this row) fp16
#pragma unroll
    for (int i = 0; i < 6; ++i) {
      int ch = t + 128 * i;        // 768 = 48 src x 16 chunks
      int s = ch >> 4, cc = ch & 15;
      int sx = xb - 20 + s;
      half8 val = h8zero();
      if (sx >= 0 && sx < WD)
        val = *(const half8*)(Vh + (size_t)(sy * WD + sx) * CD + cc * 8);
      *(half8*)&fvs[s][cc * 8] = val;
    }
    // weights: for query m=(sy,sx), output n: w = exp(corr_m[n]-mx_m)*inv_m
#pragma unroll
    for (int i = 0; i < 6; ++i) {
      int idx = t + 128 * i;  // 768 = 48 src x 16 out
      int s = idx >> 4, o = idx & 15;
      int sx = xb - 20 + s;
      int ny = yb + (o >> 3), nx = xb + (o & 7);
      int ddy = ny - sy, ddx = nx - sx;
      float wval = 0.0f;
      if (sx >= 0 && sx < WD && ddy >= -20 && ddy <= 20 && ddx >= -20 &&
          ddx <= 20) {
        int tile_m = (sy >> 1) * 8 + (sx >> 3);
        int q_m = (sy & 1) * 8 + (sx & 7);
        int slot = ny - (sy & ~1) + 20;       // in [0,41]
        int srcs = nx - (sx & ~7) + 20;       // in [0,47]
        float raw = (float)corrB[((size_t)tile_m * 42 + slot) * 768 +
                                 q_m * 48 + srcs];
        float2 st2 = *(const float2*)(stats + (size_t)(sy * WD + sx) * 2);
        wval = __expf(raw - st2.x) * st2.y;
      }
      Wsh[s][o] = wval;
    }
    __syncthreads();

    int sbeg = wv * 24;
    for (int s = sbeg; s < sbeg + 24; ++s) {
      half8 f8 = *(const half8*)&fvs[s][c8];
      float4 w4 = *(const float4*)&Wsh[s][o4];
      float fv[8];
#pragma unroll
      for (int e = 0; e < 8; ++e) fv[e] = (float)f8[e];
      float wq[4] = {w4.x, w4.y, w4.z, w4.w};
#pragma unroll
      for (int oi = 0; oi < 4; ++oi)
#pragma unroll
        for (int e = 0; e < 8; ++e)
          acc[oi][e] = fmaf(wq[oi], fv[e], acc[oi][e]);
    }
  }

  // cross-wave reduce (wave1 -> LDS, wave0 adds) then write partial.
  __syncthreads();
  if (wv == 1) {
#pragma unroll
    for (int oi = 0; oi < 4; ++oi)
#pragma unroll
      for (int cj = 0; cj < 8; ++cj) red2[lane][oi * 8 + cj] = acc[oi][cj];
  }
  __syncthreads();
  if (wv == 0) {
    float* part = ws + OFF_PART + (size_t)(chunk * BB + b) * CD * HWN;
#pragma unroll
    for (int oi = 0; oi < 4; ++oi) {
      int o = o4 + oi;
      int n = (yb + (o >> 3)) * WD + xb + (o & 7);
#pragma unroll
      for (int cj = 0; cj < 8; ++cj) {
        float s = acc[oi][cj] + red2[lane][oi * 8 + cj];
        part[(size_t)(c8 + cj) * HWN + n] = s;
      }
    }
  }
}

// ---------------- reduce partials + residual ------------------------------
__global__ __launch_bounds__(256) void reduce_kernel(
    const float* __restrict__ fmo, const float* __restrict__ gamma,
    const float* __restrict__ ws, float* __restrict__ out) {
  size_t i4 = (size_t)blockIdx.x * 256 + threadIdx.x;
  const float4* f4 = (const float4*)fmo;
  float4 base = f4[i4];
  float4 s = make_float4(0.0f, 0.0f, 0.0f, 0.0f);
  const float4* part = (const float4*)(ws + OFF_PART);
#pragma unroll
  for (int ch = 0; ch < NACH; ++ch) {
    float4 p = part[(size_t)ch * (BB * CD * HWN / 4) + i4];
    s.x += p.x; s.y += p.y; s.z += p.z; s.w += p.w;
  }
  float gm = gamma[0];
  float4 o;
  o.x = base.x + gm * s.x;
  o.y = base.y + gm * s.y;
  o.z = base.z + gm * s.z;
  o.w = base.w + gm * s.w;
  ((float4*)out)[i4] = o;
}

extern "C" void kernel_launch(void* const* d_in, const int* in_sizes, int n_in,
                              void* d_out, int out_size, void* d_ws,
                              size_t ws_size, hipStream_t stream) {
  (void)in_sizes; (void)n_in; (void)out_size; (void)ws_size;
  const float* fctx = (const float*)d_in[0];
  const float* fmo  = (const float*)d_in[1];
  const float* wqk  = (const float*)d_in[3];
  const float* wvv  = (const float*)d_in[4];
  const float* gamma = (const float*)d_in[5];
  const float* win  = (const float*)d_in[6];
  const float* bin  = (const float*)d_in[7];
  const float* wdw  = (const float*)d_in[8];
  const float* bdw  = (const float*)d_in[9];
  const float* wofs = (const float*)d_in[10];
  const float* wa   = (const float*)d_in[11];
  const float* ba   = (const float*)d_in[12];
  const float* lam  = (const float*)d_in[13];
  float* ws = (float*)d_ws;
  float* out = (float*)d_out;

  qkv_kernel<<<dim3(768), dim3(256), 0, stream>>>(fctx, fmo, wqk, wvv, ws);
  dgm_kernel<<<dim3(24), dim3(256), 0, stream>>>(win, bin, wdw, bdw, wofs, wa,
                                                 ba, lam, ws);
  logits_kernel<<<dim3(BB * 192 * 42), dim3(64), 0, stream>>>(ws);
  stats_kernel<<<dim3(1536), dim3(256), 0, stream>>>(ws);
  agg_kernel<<<dim3(BB * 192 * NACH), dim3(128), 0, stream>>>(ws);
  reduce_kernel<<<dim3(768), dim3(256), 0, stream>>>(fmo, gamma, ws, out);
}